// Round 6
// baseline (93.301 us; speedup 1.0000x reference)
//
#include <hip/hip_runtime.h>

#define B_ 64
#define TX_ 2048
#define DA_ 256
#define DS_ 256
#define H_ 50

typedef __attribute__((ext_vector_type(4))) float f32x4;
typedef __attribute__((ext_vector_type(8))) short short8;

// bf16 RNE helpers (prep only)
__device__ __forceinline__ unsigned short f2bf(float x) {
  unsigned int u = __builtin_bit_cast(unsigned int, x);
  u += 0x7FFFu + ((u >> 16) & 1u);
  return (unsigned short)(u >> 16);
}
__device__ __forceinline__ float bf2f(unsigned short h) {
  unsigned int u = ((unsigned int)h) << 16;
  return __builtin_bit_cast(float, u);
}
__device__ __forceinline__ unsigned bitf(float x) {
  return __builtin_bit_cast(unsigned, x);
}
// pack hi16 of (x,y) into one dword: halfword0 = hi(x), halfword1 = hi(y)
__device__ __forceinline__ unsigned pack_hi(float x, float y) {
  return __builtin_amdgcn_perm(bitf(y), bitf(x), 0x07060302);
}
// truncate-to-bf16 as f32 (zero low mantissa)
__device__ __forceinline__ float trunc_bf(float x) {
  return __builtin_bit_cast(float, bitf(x) & 0xFFFF0000u);
}

// ws layout (float units): num[16384] @0 | den[64] @16384 | c_ws[64*64] @16448
// | w2p[64] @20544 | wsB (32768 ushort = 64KB) @float 20608
#define WS_NUM 0
#define WS_DEN 16384
#define WS_C   16448
#define WS_W2  20544
#define WS_B   20608

// ---------------------------------------------------------------------------
// prep: zero num/den; c[b][h] = b1[h] + s@W1s (padded to 64); w2 padded;
// W1a split hi/lo (RNE) into MFMA B-fragment order.
// ---------------------------------------------------------------------------
__global__ __launch_bounds__(256) void prep_kernel(
    const float* __restrict__ s, const float* __restrict__ W1,
    const float* __restrict__ b1, const float* __restrict__ W2,
    float* __restrict__ ws)
{
  const int b = blockIdx.x;
  const int t = threadIdx.x;
  float* num = ws + WS_NUM;
  float* den = ws + WS_DEN;
  float* cws = ws + WS_C;
  float* w2p = ws + WS_W2;
  unsigned short* wsB = (unsigned short*)(ws + WS_B);

  num[b * 256 + t] = 0.0f;
  if (t == 0) den[b] = 0.0f;

  {
    const int h4 = t >> 2, kq = t & 3;
    float cp = 0.0f;
    if (h4 < H_) {
      const float* srow = s + b * DS_;
      #pragma unroll 8
      for (int k = kq * 64; k < kq * 64 + 64; ++k)
        cp += srow[k] * W1[(size_t)(DA_ + k) * H_ + h4];
    }
    cp += __shfl_down(cp, 1);
    cp += __shfl_down(cp, 2);
    if (kq == 0) cws[b * 64 + h4] = (h4 < H_) ? (cp + b1[h4]) : 0.0f;
  }
  if (b == 0 && t < 64) w2p[t] = (t < H_) ? W2[t] : 0.0f;

  #pragma unroll
  for (int ii = 0; ii < 2; ++ii) {
    const int idx = (b * 256 + t) * 2 + ii;
    const int j = idx & 7;
    const int l = (idx >> 3) & 63;
    const int nt = (idx >> 9) & 3;
    const int term = (idx >> 11) & 1;
    const int c = idx >> 12;
    const int k = c * 32 + (l >> 4) * 8 + j;
    const int n = nt * 16 + (l & 15);
    const float wv = (n < H_) ? W1[(size_t)k * H_ + n] : 0.0f;
    const unsigned short hi = f2bf(wv);
    const unsigned short val = term == 0 ? hi : f2bf(wv - bf2f(hi));
    wsB[((size_t)((c * 2 + term) * 4 + nt)) * 512 + l * 8 + j] = val;
  }
}

// ---------------------------------------------------------------------------
// fused: grid 2048 x 256 (4 waves). Block = 64 rows of one batch.
// Pass 1 (barrier-free): 2-slot f32 staging ring (16 KB) + bf16 tile written
// back from A-fragments (32 KB) -> 52 KB LDS -> 3 blocks/CU (12 waves).
// Wave w stages/reads only rows [16w,16w+16) -> per-wave counted vmcnt.
// vmcnt(10) guarantees stage(c) retired for ANY intra-region compiler order
// (only STAGE(c+1)+B(c+1)=10 VMEM ops can be younger); vmcnt(0) at c=7.
// Pass 2: wave-local weighted sum over own 16 bf16 rows; softmax weights
// broadcast by shfl (butterfly leaves row-sums in all 16 lanes); one barrier.
// ---------------------------------------------------------------------------
__global__ __launch_bounds__(256, 3) void fused_kernel(
    const float* __restrict__ a, const float* __restrict__ ws_f,
    const float* __restrict__ b2, float* __restrict__ num,
    float* __restrict__ den)
{
  __shared__ float ring[2][2048];          // 16 KB staging (slot = c&1)
  __shared__ unsigned short bt[64][256];   // 32 KB bf16 tile (row-XOR swizzled)
  __shared__ float partial[4][256];        // 4 KB cross-wave combine

  const int t = threadIdx.x;
  const int l = t & 63;
  const int w = __builtin_amdgcn_readfirstlane(t >> 6);
  const int blk = blockIdx.x;
  const int b = blk >> 5;          // 32 blocks per batch
  const long R0 = (long)blk * 64;  // first global row

  const float* cws = ws_f + WS_C;
  const float* w2p = ws_f + WS_W2;
  const unsigned short* wsB = (const unsigned short*)(ws_f + WS_B);

  float cv[4], w2v[4];
  #pragma unroll
  for (int nt = 0; nt < 4; ++nt) {
    const int n = nt * 16 + (l & 15);
    cv[nt] = cws[b * 64 + n];
    w2v[nt] = w2p[n];
  }
  const float b2v = b2[0];

  // Stage chunk c into ring slot c&1: wave w stages its own rows.
  // LDS dest linear; global source pre-swizzled (16B-unit ^ (row&7)).
  #define STAGE(c)                                                             \
    {                                                                          \
      _Pragma("unroll")                                                        \
      for (int i = 0; i < 2; ++i) {                                            \
        const int slot = w * 2 + i;                                            \
        const long gbyte = (R0 + slot * 8 + (l >> 3)) * 1024 + (c) * 128 +     \
                           (((l & 7) ^ ((l >> 3) & 7)) * 16);                  \
        __builtin_amdgcn_global_load_lds(                                      \
            (const __attribute__((address_space(1))) void*)((const char*)a +   \
                                                            gbyte),            \
            (__attribute__((address_space(3))) void*)&ring[(c) & 1]            \
                                                         [slot * 256],         \
            16, 0, 0);                                                         \
      }                                                                        \
    }

  // Prologue: stage chunk 0, prefetch B(0).
  STAGE(0);
  short8 Bh[2][4], Bl[2][4];
  {
    const short8* Bp = (const short8*)wsB;
    #pragma unroll
    for (int nt = 0; nt < 4; ++nt) {
      Bh[0][nt] = Bp[nt * 64 + l];
      Bl[0][nt] = Bp[(4 + nt) * 64 + l];
    }
  }

  f32x4 acc[4];
  #pragma unroll
  for (int nt = 0; nt < 4; ++nt) acc[nt] = (f32x4){0.f, 0.f, 0.f, 0.f};

  const int row = w * 16 + (l & 15);
  const int mask = (l & 7) << 4;
  const int obase = (l >> 4) * 32;

  #pragma unroll
  for (int c = 0; c < 8; ++c) {
    if (c + 1 < 8) {
      STAGE(c + 1);
      const short8* Bp = (const short8*)(wsB + (size_t)(c + 1) * 4096);
      #pragma unroll
      for (int nt = 0; nt < 4; ++nt) {
        Bh[(c + 1) & 1][nt] = Bp[nt * 64 + l];
        Bl[(c + 1) & 1][nt] = Bp[(4 + nt) * 64 + l];
      }
    }
    if (c < 7) asm volatile("s_waitcnt vmcnt(10)" ::: "memory");
    else       asm volatile("s_waitcnt vmcnt(0)" ::: "memory");
    __builtin_amdgcn_sched_barrier(0);

    // A-fragment from this wave's own staged rows (f32)
    const char* tb = (const char*)&ring[c & 1][0] + row * 128;
    const float4 v0 = *(const float4*)(tb + (obase ^ mask));
    const float4 v1 = *(const float4*)(tb + ((obase + 16) ^ mask));
    const float av[8] = {v0.x, v0.y, v0.z, v0.w, v1.x, v1.y, v1.z, v1.w};

    // hi = truncate-to-bf16 (perm-pack), lo = a - hi (truncate-pack too)
    unsigned hu[4], lu[4];
    #pragma unroll
    for (int p = 0; p < 4; ++p) {
      const float x = av[2 * p], y = av[2 * p + 1];
      hu[p] = pack_hi(x, y);
      lu[p] = pack_hi(x - trunc_bf(x), y - trunc_bf(y));
    }
    const short8 Ah = __builtin_bit_cast(short8, *(uint4*)hu);
    const short8 Al = __builtin_bit_cast(short8, *(uint4*)lu);

    // write bf16(hi) back for pass 2: 16B at byte 2*(c*32+(l>>4)*8), row-XOR
    *(short8*)((char*)&bt[row][0] +
               ((c * 64 + (l >> 4) * 16) ^ mask)) = Ah;

    #pragma unroll
    for (int nt = 0; nt < 4; ++nt) {
      acc[nt] = __builtin_amdgcn_mfma_f32_16x16x32_bf16(Ah, Bh[c & 1][nt], acc[nt], 0, 0, 0);
      acc[nt] = __builtin_amdgcn_mfma_f32_16x16x32_bf16(Ah, Bl[c & 1][nt], acc[nt], 0, 0, 0);
      acc[nt] = __builtin_amdgcn_mfma_f32_16x16x32_bf16(Al, Bh[c & 1][nt], acc[nt], 0, 0, 0);
    }
  }
  #undef STAGE

  // Epilogue: e -> w (all lanes; butterfly leaves row-sum in all 16 lanes).
  // wr[r] = w for row (w*16 + (l>>4)*4 + r), identical across each 16-group.
  float wr[4];
  #pragma unroll
  for (int r = 0; r < 4; ++r) {
    float e = 0.0f;
    #pragma unroll
    for (int nt = 0; nt < 4; ++nt)
      e += fmaxf(acc[nt][r] + cv[nt], 0.0f) * w2v[nt];
    e += __shfl_xor(e, 1);
    e += __shfl_xor(e, 2);
    e += __shfl_xor(e, 4);
    e += __shfl_xor(e, 8);
    e += b2v;
    const float th = 1.0f - 2.0f / (__expf(2.0f * e) + 1.0f);  // tanh(e)
    wr[r] = __expf(th);
  }

  // Pass 2 (wave-local): ctx_partial[d] = sum over own 16 rows of w[r]*a[r][d]
  f32x4 csum = (f32x4){0.f, 0.f, 0.f, 0.f};
  float wsum = 0.0f;
  #pragma unroll
  for (int r = 0; r < 16; ++r) {
    const float wv = __shfl(wr[r & 3], (r >> 2) * 16);
    wsum += wv;
    const int grow = w * 16 + r;
    const uint2 u = *(const uint2*)((const char*)&bt[grow][0] +
                                    ((8 * l) ^ ((grow & 7) << 4)));
    const float f0 = __builtin_bit_cast(float, u.x << 16);
    const float f1 = __builtin_bit_cast(float, u.x & 0xFFFF0000u);
    const float f2 = __builtin_bit_cast(float, u.y << 16);
    const float f3 = __builtin_bit_cast(float, u.y & 0xFFFF0000u);
    csum.x += wv * f0;
    csum.y += wv * f1;
    csum.z += wv * f2;
    csum.w += wv * f3;
  }
  if (l == 0) atomicAdd(&den[b], wsum);
  *(f32x4*)&partial[w][4 * l] = csum;
  __syncthreads();  // the only block-wide barrier

  // flush: thread t sums 4 wave partials for column t, one global atomic
  {
    const float v = partial[0][t] + partial[1][t] + partial[2][t] + partial[3][t];
    atomicAdd(&num[b * 256 + t], v);
  }
}

// ---------------------------------------------------------------------------
// finish: out = num / den
// ---------------------------------------------------------------------------
__global__ __launch_bounds__(256) void finish_kernel(
    const float* __restrict__ ws_f, float* __restrict__ out)
{
  const int b = blockIdx.x;
  const int t = threadIdx.x;
  out[b * 256 + t] = ws_f[WS_NUM + b * 256 + t] / ws_f[WS_DEN + b];
}

extern "C" void kernel_launch(void* const* d_in, const int* in_sizes, int n_in,
                              void* d_out, int out_size, void* d_ws, size_t ws_size,
                              hipStream_t stream) {
  const float* a  = (const float*)d_in[0];
  const float* s  = (const float*)d_in[1];
  const float* W1 = (const float*)d_in[2];
  const float* b1 = (const float*)d_in[3];
  const float* W2 = (const float*)d_in[4];
  const float* b2 = (const float*)d_in[5];
  float* out = (float*)d_out;
  float* ws  = (float*)d_ws;

  prep_kernel<<<dim3(B_), dim3(256), 0, stream>>>(s, W1, b1, W2, ws);
  fused_kernel<<<dim3(2048), dim3(256), 0, stream>>>(
      a, ws, b2, ws + WS_NUM, ws + WS_DEN);
  finish_kernel<<<dim3(B_), dim3(256), 0, stream>>>(ws, out);
}

// Round 7
// 53.230 us; speedup vs baseline: 1.7528x; 1.7528x over previous
//
#include <hip/hip_runtime.h>

#define B_ 64
#define TX_ 2048
#define DA_ 256
#define DS_ 256
#define H_ 50

typedef __attribute__((ext_vector_type(4))) float f32x4;
typedef __attribute__((ext_vector_type(8))) short short8;

// bf16 RNE helpers (prep only)
__device__ __forceinline__ unsigned short f2bf(float x) {
  unsigned int u = __builtin_bit_cast(unsigned int, x);
  u += 0x7FFFu + ((u >> 16) & 1u);
  return (unsigned short)(u >> 16);
}
__device__ __forceinline__ float bf2f(unsigned short h) {
  unsigned int u = ((unsigned int)h) << 16;
  return __builtin_bit_cast(float, u);
}
__device__ __forceinline__ unsigned bitf(float x) {
  return __builtin_bit_cast(unsigned, x);
}
// pack hi16 of (x,y) into one dword: halfword0 = hi(x), halfword1 = hi(y)
__device__ __forceinline__ unsigned pack_hi(float x, float y) {
  return __builtin_amdgcn_perm(bitf(y), bitf(x), 0x07060302);
}
// truncate-to-bf16 as f32 (zero low mantissa)
__device__ __forceinline__ float trunc_bf(float x) {
  return __builtin_bit_cast(float, bitf(x) & 0xFFFF0000u);
}

// ws layout (float units): num[16384] @0 | den[64] @16384 | c_ws[64*64] @16448
// | w2p[64] @20544 | wsB (32768 ushort = 64KB) @float 20608
#define WS_NUM 0
#define WS_DEN 16384
#define WS_C   16448
#define WS_W2  20544
#define WS_B   20608

// ---------------------------------------------------------------------------
// prep: grid 192 x 256.
// Blocks 0-63 (b=blk): zero num/den, c[b][h] = b1[h] + s@W1s (padded), w2 pad.
// Blocks 64-191: W1a split hi/lo (RNE) into MFMA B-fragment order, 1/thread.
// ---------------------------------------------------------------------------
__global__ __launch_bounds__(256) void prep_kernel(
    const float* __restrict__ s, const float* __restrict__ W1,
    const float* __restrict__ b1, const float* __restrict__ W2,
    float* __restrict__ ws)
{
  const int blk = blockIdx.x;
  const int t = threadIdx.x;
  unsigned short* wsB = (unsigned short*)(ws + WS_B);

  if (blk < 64) {
    const int b = blk;
    ws[WS_NUM + b * 256 + t] = 0.0f;
    if (t == 0) ws[WS_DEN + b] = 0.0f;

    const int h4 = t >> 2, kq = t & 3;
    float cp = 0.0f;
    if (h4 < H_) {
      const float* srow = s + b * DS_;
      #pragma unroll 8
      for (int k = kq * 64; k < kq * 64 + 64; ++k)
        cp += srow[k] * W1[(size_t)(DA_ + k) * H_ + h4];
    }
    cp += __shfl_down(cp, 1);
    cp += __shfl_down(cp, 2);
    if (kq == 0) ws[WS_C + b * 64 + h4] = (h4 < H_) ? (cp + b1[h4]) : 0.0f;
    if (b == 0 && t < 64) ws[WS_W2 + t] = (t < H_) ? W2[t] : 0.0f;
  } else {
    const int idx = (blk - 64) * 256 + t;  // [0, 32768)
    const int j = idx & 7;
    const int l = (idx >> 3) & 63;
    const int nt = (idx >> 9) & 3;
    const int term = (idx >> 11) & 1;
    const int c = idx >> 12;
    const int k = c * 32 + (l >> 4) * 8 + j;
    const int n = nt * 16 + (l & 15);
    const float wv = (n < H_) ? W1[(size_t)k * H_ + n] : 0.0f;
    const unsigned short hi = f2bf(wv);
    const unsigned short val = term == 0 ? hi : f2bf(wv - bf2f(hi));
    wsB[((size_t)((c * 2 + term) * 4 + nt)) * 512 + l * 8 + j] = val;
  }
}

// ---------------------------------------------------------------------------
// fused: grid 2048 x 256 (4 waves). Block = 64 rows of one batch.
// R5 structure (known-good): full 64KB f32 tile, STAGE depth-2, barrier-free
// pass 1 (wave w stages AND reads only rows [16w,16w+16)), per-wave counted
// vmcnt. In-loop VMEM is exactly stages+B loads (epilogue constants loaded
// AFTER the loop), so the counts are exact:
//   at iter c outstanding (old->new): stage(c)2, B(c)8, stage(c+1)2, B(c+1)8,
//   stage(c+2)2 => vmcnt(10) drains stage(c)+B(c); c==6: vmcnt(8); c==7: 0.
// __launch_bounds__(256,2): LDS caps at 2 blocks/CU anyway; give the RA
// headroom (up to 256 VGPR) to keep the B double-buffer register-resident.
// ---------------------------------------------------------------------------
__global__ __launch_bounds__(256, 2) void fused_kernel(
    const float* __restrict__ a, const float* __restrict__ ws_f,
    const float* __restrict__ b2, float* __restrict__ num,
    float* __restrict__ den)
{
  __shared__ float tile[16384];  // 64KB: chunk c at floats [c*2048, +2048)
  __shared__ float w_sh[64];

  const int t = threadIdx.x;
  const int l = t & 63;
  const int w = __builtin_amdgcn_readfirstlane(t >> 6);
  const int blk = blockIdx.x;
  const int b = blk >> 5;          // 32 blocks per batch
  const long R0 = (long)blk * 64;  // first global row

  const unsigned short* wsB = (const unsigned short*)(ws_f + WS_B);

  // Stage chunk c: wave w stages its own rows. LDS dest linear; global source
  // pre-swizzled (16B-slot ^ (row&7)) so later tile reads are spread.
  #define STAGE(c)                                                             \
    {                                                                          \
      _Pragma("unroll")                                                        \
      for (int i = 0; i < 2; ++i) {                                            \
        const int slot = w * 2 + i;                                            \
        const long gbyte = (R0 + slot * 8 + (l >> 3)) * 1024 + (c) * 128 +     \
                           (((l & 7) ^ ((l >> 3) & 7)) * 16);                  \
        __builtin_amdgcn_global_load_lds(                                      \
            (const __attribute__((address_space(1))) void*)((const char*)a +   \
                                                            gbyte),            \
            (__attribute__((address_space(3))) void*)&tile[(c)*2048 +          \
                                                           slot * 256],        \
            16, 0, 0);                                                         \
      }                                                                        \
    }

  STAGE(0);
  STAGE(1);

  // B double-buffer in registers; prologue loads chunk 0 into set 0.
  short8 Bh[2][4], Bl[2][4];
  {
    const short8* Bp = (const short8*)wsB;
    #pragma unroll
    for (int nt = 0; nt < 4; ++nt) {
      Bh[0][nt] = Bp[nt * 64 + l];
      Bl[0][nt] = Bp[(4 + nt) * 64 + l];
    }
  }

  f32x4 acc[4];
  #pragma unroll
  for (int nt = 0; nt < 4; ++nt) acc[nt] = (f32x4){0.f, 0.f, 0.f, 0.f};

  const int row = w * 16 + (l & 15);
  const int mask = (l & 7) << 4;
  const int obase = (l >> 4) * 32;

  #pragma unroll
  for (int c = 0; c < 8; ++c) {
    if (c + 2 < 8) STAGE(c + 2);
    if (c + 1 < 8) {
      const short8* Bp = (const short8*)(wsB + (size_t)(c + 1) * 4096);
      #pragma unroll
      for (int nt = 0; nt < 4; ++nt) {
        Bh[(c + 1) & 1][nt] = Bp[nt * 64 + l];
        Bl[(c + 1) & 1][nt] = Bp[(4 + nt) * 64 + l];
      }
    }
    if (c < 6)       asm volatile("s_waitcnt vmcnt(10)" ::: "memory");
    else if (c == 6) asm volatile("s_waitcnt vmcnt(8)" ::: "memory");
    else             asm volatile("s_waitcnt vmcnt(0)" ::: "memory");
    __builtin_amdgcn_sched_barrier(0);

    // A-fragment from this wave's own staged rows (f32)
    const char* tb = (const char*)tile + (size_t)c * 8192 + row * 128;
    const float4 v0 = *(const float4*)(tb + (obase ^ mask));
    const float4 v1 = *(const float4*)(tb + ((obase + 16) ^ mask));
    const float av[8] = {v0.x, v0.y, v0.z, v0.w, v1.x, v1.y, v1.z, v1.w};

    // hi = truncate-to-bf16 (perm-pack), lo = a - hi
    unsigned hu[4], lu[4];
    #pragma unroll
    for (int p = 0; p < 4; ++p) {
      const float x = av[2 * p], y = av[2 * p + 1];
      hu[p] = pack_hi(x, y);
      lu[p] = pack_hi(x - trunc_bf(x), y - trunc_bf(y));
    }
    const short8 Ah = __builtin_bit_cast(short8, *(uint4*)hu);
    const short8 Al = __builtin_bit_cast(short8, *(uint4*)lu);

    #pragma unroll
    for (int nt = 0; nt < 4; ++nt) {
      acc[nt] = __builtin_amdgcn_mfma_f32_16x16x32_bf16(Ah, Bh[c & 1][nt], acc[nt], 0, 0, 0);
      acc[nt] = __builtin_amdgcn_mfma_f32_16x16x32_bf16(Ah, Bl[c & 1][nt], acc[nt], 0, 0, 0);
      acc[nt] = __builtin_amdgcn_mfma_f32_16x16x32_bf16(Al, Bh[c & 1][nt], acc[nt], 0, 0, 0);
    }
  }
  #undef STAGE

  // Epilogue constants loaded NOW (not needed earlier; keeps in-loop vmcnt
  // arithmetic exact and avoids any pre-loop LDS race).
  float cv[4], w2v[4];
  #pragma unroll
  for (int nt = 0; nt < 4; ++nt) {
    const int n = nt * 16 + (l & 15);
    cv[nt] = ws_f[WS_C + b * 64 + n];
    w2v[nt] = ws_f[WS_W2 + n];
  }
  const float b2v = b2[0];

  // e -> w. C layout: n = nt*16+(l&15), row = w*16+(l>>4)*4+r
  #pragma unroll
  for (int r = 0; r < 4; ++r) {
    float e = 0.0f;
    #pragma unroll
    for (int nt = 0; nt < 4; ++nt)
      e += fmaxf(acc[nt][r] + cv[nt], 0.0f) * w2v[nt];
    e += __shfl_xor(e, 1);
    e += __shfl_xor(e, 2);
    e += __shfl_xor(e, 4);
    e += __shfl_xor(e, 8);
    e += b2v;
    const float th = 1.0f - 2.0f / (__expf(2.0f * e) + 1.0f);  // tanh(e)
    if ((l & 15) == 0) w_sh[w * 16 + (l >> 4) * 4 + r] = __expf(th);
  }
  __syncthreads();  // the only block-wide barrier (w_sh + tile for pass 2)

  // Denominator partial (wave 0)
  if (t < 64) {
    float v = w_sh[t];
    #pragma unroll
    for (int off = 32; off > 0; off >>= 1) v += __shfl_xor(v, off);
    if (t == 0) atomicAdd(&den[b], v);
  }

  // Pass 2: context partials from the f32 LDS tile. Thread t owns column t:
  // chunk = t>>5, col-in-chunk = t&31 (2-way bank aliasing = free).
  {
    const int cc = t >> 5, col = t & 31;
    const char* tb = (const char*)tile + (size_t)cc * 8192;
    float sum = 0.0f;
    #pragma unroll 8
    for (int r = 0; r < 64; ++r) {
      const float av = *(const float*)(tb + r * 128 + ((col * 4) ^ ((r & 7) << 4)));
      sum += w_sh[r] * av;
    }
    atomicAdd(&num[b * 256 + t], sum);
  }
}

// ---------------------------------------------------------------------------
// finish: out = num / den
// ---------------------------------------------------------------------------
__global__ __launch_bounds__(256) void finish_kernel(
    const float* __restrict__ ws_f, float* __restrict__ out)
{
  const int b = blockIdx.x;
  const int t = threadIdx.x;
  out[b * 256 + t] = ws_f[WS_NUM + b * 256 + t] / ws_f[WS_DEN + b];
}

extern "C" void kernel_launch(void* const* d_in, const int* in_sizes, int n_in,
                              void* d_out, int out_size, void* d_ws, size_t ws_size,
                              hipStream_t stream) {
  const float* a  = (const float*)d_in[0];
  const float* s  = (const float*)d_in[1];
  const float* W1 = (const float*)d_in[2];
  const float* b1 = (const float*)d_in[3];
  const float* W2 = (const float*)d_in[4];
  const float* b2 = (const float*)d_in[5];
  float* out = (float*)d_out;
  float* ws  = (float*)d_ws;

  prep_kernel<<<dim3(192), dim3(256), 0, stream>>>(s, W1, b1, W2, ws);
  fused_kernel<<<dim3(2048), dim3(256), 0, stream>>>(
      a, ws, b2, ws + WS_NUM, ws + WS_DEN);
  finish_kernel<<<dim3(B_), dim3(256), 0, stream>>>(ws, out);
}